// Round 3
// baseline (358.026 us; speedup 1.0000x reference)
//
#include <hip/hip_runtime.h>

// Fused SNN, MFMA + LDS-free LIF. MI355X (gfx950).
// Per wave: 16 rows. GEMM1 (conv as banded Toeplitz matmul, bf16 MFMA) ->
// threshold/count -> spikes to per-wave LDS -> GEMM2 (cur1 = S @ W1^T, MFMA)
// -> cur1 to regs (4 lanes/row, 13 h each) -> 25-step LIF with W2 in VGPRs,
// quad reduce via DPP (VALU pipe), coalesced per-step stores.

typedef float  f32x4 __attribute__((ext_vector_type(4)));
typedef short  s16x8 __attribute__((ext_vector_type(8)));

constexpr int L  = 187;
constexpr int H  = 50;
constexpr int NST = 25;
constexpr int KP = 192;
constexpr float BETA = 0.95f;
constexpr float YTH  = 0.25f;    // y*2 > 0.5  <=>  y > 0.25

__device__ inline unsigned short f2bf(float f) {
    union { float f; unsigned u; } v; v.f = f;
    return (unsigned short)((v.u + 0x7FFFu + ((v.u >> 16) & 1u)) >> 16);  // RNE
}

// quad (4-lane) butterfly sum on the VALU pipe (DPP quad_perm), no LDS.
__device__ inline float quad_add(float v) {
    v += __int_as_float(__builtin_amdgcn_update_dpp(
            0, __float_as_int(v), 0xB1, 0xF, 0xF, true));   // quad_perm(1,0,3,2)
    v += __int_as_float(__builtin_amdgcn_update_dpp(
            0, __float_as_int(v), 0x4E, 0xF, 0xF, true));   // quad_perm(2,3,0,1)
    return v;
}

// Tt[n][k] = filt[k-n+24] (bf16, banded), W1f[h][k] = W1[h][k] (bf16, padded)
__global__ void __launch_bounds__(256) prep_mats(
    const float* __restrict__ filt, const float* __restrict__ W1,
    unsigned short* __restrict__ Tt, unsigned short* __restrict__ W1f)
{
    int i = blockIdx.x * 256 + threadIdx.x;
    if (i < KP * KP) {
        int n = i / KP, k = i - n * KP;
        int d = k - n + 24;
        unsigned short v = 0;
        if (n < L && k < L && d >= 0 && d < 50) v = f2bf(filt[d]);
        Tt[i] = v;
    } else {
        int i2 = i - KP * KP;
        if (i2 < 64 * KP) {
            int h = i2 / KP, k = i2 - h * KP;
            unsigned short v = 0;
            if (h < H && k < L) v = f2bf(W1[h * L + k]);
            W1f[i2] = v;
        }
    }
}

__global__ void __launch_bounds__(256, 4) snn_main(
    const float* __restrict__ x, const unsigned short* __restrict__ Tt,
    const unsigned short* __restrict__ W1f, const float* __restrict__ W2,
    float* __restrict__ out, unsigned int* __restrict__ cnt, int B)
{
    __shared__ unsigned short Sl[4][16][200];   // spike tile / cur1 overlay

    const int tid = threadIdx.x;
    const int wid = tid >> 6, lane = tid & 63;
    const int lm = lane & 15, lk = lane >> 4;
    const int rowbase = blockIdx.x * 64 + wid * 16;

    // ---------- A fragments: 1 m-tile x 6 k-tiles, bf16 ----------
    s16x8 a1[6];
    {
        const float* __restrict__ xr = x + (size_t)(rowbase + lm) * L;
        #pragma unroll
        for (int kt = 0; kt < 6; ++kt) {
            s16x8 v;
            #pragma unroll
            for (int j = 0; j < 8; ++j) {
                int k = kt * 32 + lk * 8 + j;
                v[j] = (short)f2bf((k < L) ? xr[k] : 0.f);
            }
            a1[kt] = v;
        }
    }

    // ---------- GEMM1: conv, threshold, spikes + count ----------
    int scnt = 0;
    #pragma unroll
    for (int nt = 0; nt < 12; ++nt) {
        constexpr int lo[12] = {0,0,0,0,1,1,2,2,3,3,4,4};
        constexpr int hi[12] = {1,1,2,2,3,3,4,4,5,5,5,5};
        f32x4 acc = {0, 0, 0, 0};
        #pragma unroll
        for (int kt = 0; kt < 6; ++kt) {
            if (kt >= lo[nt] && kt <= hi[nt]) {
                s16x8 b = *(const s16x8*)(Tt + (nt * 16 + lm) * KP + kt * 32 + lk * 8);
                acc = __builtin_amdgcn_mfma_f32_16x16x32_bf16(a1[kt], b, acc, 0, 0, 0);
            }
        }
        #pragma unroll
        for (int j = 0; j < 4; ++j) {          // D: row = 4*lk+j, col = lm
            bool s = acc[j] > YTH;
            scnt += (int)s;
            Sl[wid][4 * lk + j][nt * 16 + lm] = s ? 0x3F80 : 0;
        }
    }

    #pragma unroll
    for (int off = 32; off; off >>= 1) scnt += __shfl_down(scnt, off);
    if (lane == 0) atomicAdd(cnt, (unsigned)scnt);

    // ---------- GEMM2: cur1 = spikes @ W1^T ----------
    f32x4 c0[4];
    #pragma unroll
    for (int n2 = 0; n2 < 4; ++n2) c0[n2] = (f32x4){0, 0, 0, 0};
    #pragma unroll
    for (int kt = 0; kt < 6; ++kt) {
        s16x8 a2 = *(const s16x8*)&Sl[wid][lm][kt * 32 + lk * 8];
        #pragma unroll
        for (int n2 = 0; n2 < 4; ++n2) {
            s16x8 b2 = *(const s16x8*)(W1f + (n2 * 16 + lm) * KP + kt * 32 + lk * 8);
            c0[n2] = __builtin_amdgcn_mfma_f32_16x16x32_bf16(a2, b2, c0[n2], 0, 0, 0);
        }
    }

    // ---------- repack cur1 -> per-wave LDS f32 [16][68] (overlay) ----------
    asm volatile("s_waitcnt lgkmcnt(0)" ::: "memory");   // Sl reads done
    float* Cl = (float*)&Sl[wid][0][0];
    #pragma unroll
    for (int n2 = 0; n2 < 4; ++n2)
        #pragma unroll
        for (int j = 0; j < 4; ++j)
            Cl[(4 * lk + j) * 68 + n2 * 16 + lm] = c0[n2][j];
    asm volatile("s_waitcnt lgkmcnt(0)" ::: "memory");

    // ---------- LIF: quad per row, 13 h per lane, W2 in VGPRs ----------
    const int r = lane >> 2, sub = lane & 3;   // row r, h in [13*sub, 13*sub+13)
    float cu[13];
    #pragma unroll
    for (int i = 0; i < 13; ++i) cu[i] = Cl[r * 68 + sub * 13 + i];

    float w2v[5][13];
    #pragma unroll
    for (int c = 0; c < 5; ++c)
        #pragma unroll
        for (int i = 0; i < 13; ++i) {
            int h = sub * 13 + i;
            w2v[c][i] = (h < H) ? W2[c * H + h] : 0.f;
        }

    float m1[13], m2[5];
    #pragma unroll
    for (int i = 0; i < 13; ++i) m1[i] = 0.f;
    #pragma unroll
    for (int c = 0; c < 5; ++c) m2[c] = 0.f;

    const size_t row = (size_t)rowbase + r;
    float* __restrict__ p0 = out + row * 5 + sub;        // my column (c = sub)
    float* __restrict__ p4 = out + row * 5 + 4;          // c = 4 (sub 0 stores)
    const size_t step = (size_t)B * 5;

    #pragma unroll 1
    for (int t = 0; t < NST; ++t) {
        float c2[5] = {0, 0, 0, 0, 0};
        #pragma unroll
        for (int i = 0; i < 13; ++i) {
            float m = fmaf(BETA, m1[i], cu[i]);
            bool s = m > 1.f;
            m1[i] = s ? m - 1.f : m;
            float spk = s ? 1.f : 0.f;
            c2[0] = fmaf(spk, w2v[0][i], c2[0]);
            c2[1] = fmaf(spk, w2v[1][i], c2[1]);
            c2[2] = fmaf(spk, w2v[2][i], c2[2]);
            c2[3] = fmaf(spk, w2v[3][i], c2[3]);
            c2[4] = fmaf(spk, w2v[4][i], c2[4]);
        }
        float sv[5];
        #pragma unroll
        for (int c = 0; c < 5; ++c) {
            float m = fmaf(BETA, m2[c], quad_add(c2[c]));
            bool s2 = m > 1.f;
            m2[c] = s2 ? m - 1.f : m;
            sv[c] = s2 ? 1.f : 0.f;
        }
        float mine = sv[0];
        mine = (sub == 1) ? sv[1] : mine;
        mine = (sub == 2) ? sv[2] : mine;
        mine = (sub == 3) ? sv[3] : mine;
        p0[0] = mine;                       // 64-lane coalesced-ish store
        if (sub == 0) p4[0] = sv[4];
        p0 += step; p4 += step;
    }
}

__global__ void finalize_count(const unsigned int* __restrict__ cnt,
                               float* __restrict__ out, size_t off)
{
    if (threadIdx.x == 0 && blockIdx.x == 0)
        out[off] = (float)((double)(*cnt) * 25.0);
}

// ================= fallback (scalar), used only if ws too small ==============
__global__ void __launch_bounds__(256) snn_fallback(
    const float* __restrict__ x, const float* __restrict__ filt,
    const float* __restrict__ W1, const float* __restrict__ W2,
    float* __restrict__ out, unsigned int* __restrict__ cnt_ws, int B)
{
    const int row = blockIdx.x * 256 + threadIdx.x;
    const bool valid = row < B;
    const int rr = valid ? row : (B - 1);
    const float* __restrict__ xr = x + (size_t)rr * L;
    float w[64], cur1[H];
    #pragma unroll
    for (int h = 0; h < H; ++h) cur1[h] = 0.f;
    int cntv = 0;
    #pragma unroll
    for (int i = 0; i < 64; ++i) w[i] = (i >= 24) ? xr[i - 24] : 0.f;
    #pragma unroll 1
    for (int s = 0; s < 12; ++s) {
        const int l0 = s * 15;
        #pragma unroll
        for (int j = 0; j < 15; ++j) {
            const int l = l0 + j;
            float y = 0.f;
            #pragma unroll
            for (int k = 0; k < 50; ++k) y = fmaf(w[j + k], filt[k], y);
            const bool sb = y > YTH;
            cntv += sb;
            const float sp = sb ? 1.f : 0.f;
            #pragma unroll
            for (int h = 0; h < H; ++h) cur1[h] = fmaf(sp, W1[h * L + l], cur1[h]);
        }
        #pragma unroll
        for (int i = 0; i < 49; ++i) w[i] = w[i + 15];
        #pragma unroll
        for (int d = 0; d < 15; ++d) {
            const int g = l0 + 40 + d;
            w[49 + d] = (g < L) ? xr[g] : 0.f;
        }
    }
    #pragma unroll
    for (int j = 0; j < 7; ++j) {
        const int l = 180 + j;
        float y = 0.f;
        #pragma unroll
        for (int k = 0; k < 50; ++k) y = fmaf(w[j + k], filt[k], y);
        const bool sb = y > YTH;
        cntv += sb;
        const float sp = sb ? 1.f : 0.f;
        #pragma unroll
        for (int h = 0; h < H; ++h) cur1[h] = fmaf(sp, W1[h * L + l], cur1[h]);
    }
    int wc = valid ? cntv : 0;
    #pragma unroll
    for (int off = 32; off; off >>= 1) wc += __shfl_down(wc, off);
    if ((threadIdx.x & 63) == 0) atomicAdd(cnt_ws, (unsigned)wc);
    float m1[H], m2[5];
    #pragma unroll
    for (int h = 0; h < H; ++h) m1[h] = 0.f;
    #pragma unroll
    for (int c = 0; c < 5; ++c) m2[c] = 0.f;
    #pragma unroll 1
    for (int t = 0; t < NST; ++t) {
        float c2[5] = {0, 0, 0, 0, 0};
        #pragma unroll
        for (int h = 0; h < H; ++h) {
            float m = fmaf(BETA, m1[h], cur1[h]);
            const float sp = (m > 1.f) ? 1.f : 0.f;
            m1[h] = m - sp;
            #pragma unroll
            for (int c = 0; c < 5; ++c) c2[c] = fmaf(sp, W2[c * H + h], c2[c]);
        }
        float* __restrict__ ot = out + ((size_t)t * B + rr) * 5;
        #pragma unroll
        for (int c = 0; c < 5; ++c) {
            float m = fmaf(BETA, m2[c], c2[c]);
            const float s2 = (m > 1.f) ? 1.f : 0.f;
            m2[c] = m - s2;
            if (valid) ot[c] = s2;
        }
    }
}

extern "C" void kernel_launch(void* const* d_in, const int* in_sizes, int n_in,
                              void* d_out, int out_size, void* d_ws, size_t ws_size,
                              hipStream_t stream)
{
    const float* x    = (const float*)d_in[0];
    const float* filt = (const float*)d_in[1];
    const float* W1   = (const float*)d_in[2];
    const float* W2   = (const float*)d_in[3];
    float* out        = (float*)d_out;
    const int B       = in_sizes[0] / L;        // 131072

    unsigned int* cnt = (unsigned int*)d_ws;
    unsigned short* Tt  = (unsigned short*)((char*)d_ws + 64);
    unsigned short* W1f = (unsigned short*)((char*)d_ws + 64 + KP * KP * 2);
    const size_t need = 64 + (size_t)KP * KP * 2 + (size_t)64 * KP * 2;

    hipMemsetAsync(cnt, 0, sizeof(unsigned int), stream);

    if (ws_size >= need && (B % 64) == 0) {
        prep_mats<<<(KP * KP + 64 * KP + 255) / 256, 256, 0, stream>>>(filt, W1, Tt, W1f);
        snn_main<<<B / 64, 256, 0, stream>>>(x, Tt, W1f, W2, out, cnt, B);
    } else {
        snn_fallback<<<(B + 255) / 256, 256, 0, stream>>>(x, filt, W1, W2, out, cnt, B);
    }
    finalize_count<<<1, 1, 0, stream>>>(cnt, out, (size_t)NST * B * 5);
}

// Round 4
// 227.317 us; speedup vs baseline: 1.5750x; 1.5750x over previous
//
#include <hip/hip_runtime.h>

// Fused SNN, all-register MFMA pipeline. MI355X (gfx950).
//
// All GEMMs computed TRANSPOSED so each MFMA's C-layout output (col=lane&15
// = batch row) feeds the next MFMA's B-fragment without any cross-lane data
// movement. Contraction-slot bijection for GEMM2/GEMM3:
//     k_slot(lk, jj, kt) = 4*lk + (jj&3) + 16*(2*kt + (jj>>2))
// matches exactly the values a lane holds in C-layout (row = 4*lk + j + 16*nt).
// A-side operands (Toeplitz^T, W1, W2) are precomputed PRE-PERMUTED by
// prep_frags, so A and B agree. Zero LDS, zero transposes, zero lane-private
// weight arrays (W2 fragment = 8 uniform VGPRs).

typedef float f32x4 __attribute__((ext_vector_type(4)));
typedef short s16x8 __attribute__((ext_vector_type(8)));

constexpr int L = 187;
constexpr int H = 50;
constexpr int NST = 25;
constexpr float BETA = 0.95f;
constexpr float YTH  = 0.25f;      // y*2 > 0.5  <=>  y > 0.25

constexpr int TTA_SH = 12 * 6 * 64 * 8;   // TtA fragments (A of GEMM1)
constexpr int W1A_SH = 4 * 6 * 64 * 8;    // W1 fragments (A of GEMM2)
constexpr int W2A_SH = 2 * 64 * 8;        // W2 fragments (A of GEMM3)

__device__ inline unsigned short f2bf(float f) {
    union { float f; unsigned u; } v; v.f = f;
    return (unsigned short)((v.u + 0x7FFFu + ((v.u >> 16) & 1u)) >> 16);  // RNE
}

// one thread per output short; total = TTA_SH + W1A_SH + W2A_SH = 50176
__global__ void __launch_bounds__(256) prep_frags(
    const float* __restrict__ filt, const float* __restrict__ W1,
    const float* __restrict__ W2,
    unsigned short* __restrict__ TtA, unsigned short* __restrict__ W1A,
    unsigned short* __restrict__ W2A)
{
    int i = blockIdx.x * 256 + threadIdx.x;
    if (i < TTA_SH) {
        // GEMM1 A: canonical slots. A[l][k]: lane(lm,lk), l = 16*nt+lm,
        // k = 32*kt + 8*lk + jj, val = filt[k - l + 24]
        int jj = i & 7, lane = (i >> 3) & 63, kt = (i >> 9) % 6, nt = i / (512 * 6);
        int lm = lane & 15, lk = lane >> 4;
        int l = 16 * nt + lm;
        int k = 32 * kt + 8 * lk + jj;
        int d = k - l + 24;
        unsigned short v = 0;
        if (l < L && k < L && d >= 0 && d < 50) v = f2bf(filt[d]);
        TtA[i] = v;
    } else if (i < TTA_SH + W1A_SH) {
        // GEMM2 A: permuted slots. A[h][l]: h = 16*mt+lm,
        // l = 4*lk + (jj&3) + 16*(2*kt + (jj>>2)), val = W1[h][l]
        int i2 = i - TTA_SH;
        int jj = i2 & 7, lane = (i2 >> 3) & 63, kt = (i2 >> 9) % 6, mt = i2 / (512 * 6);
        int lm = lane & 15, lk = lane >> 4;
        int h = 16 * mt + lm;
        int l = 4 * lk + (jj & 3) + 16 * (2 * kt + (jj >> 2));
        unsigned short v = 0;
        if (h < H && l < L) v = f2bf(W1[h * L + l]);
        W1A[i2] = v;
    } else {
        // GEMM3 A: permuted slots. A[c][h]: c = lm,
        // h = 4*lk + (jj&3) + 16*(2*kt + (jj>>2)), val = W2[c][h]
        int i3 = i - TTA_SH - W1A_SH;
        int jj = i3 & 7, lane = (i3 >> 3) & 63, kt = i3 >> 9;   // kt = 0,1
        int lm = lane & 15, lk = lane >> 4;
        int h = 4 * lk + (jj & 3) + 16 * (2 * kt + (jj >> 2));
        unsigned short v = 0;
        if (lm < 5 && h < H) v = f2bf(W2[lm * H + h]);
        W2A[i3] = v;
    }
}

__global__ void __launch_bounds__(256) snn_main(
    const float* __restrict__ x,
    const unsigned short* __restrict__ TtA,
    const unsigned short* __restrict__ W1A,
    const unsigned short* __restrict__ W2A,
    float* __restrict__ out, unsigned int* __restrict__ cnt, int B)
{
    const int tid = threadIdx.x;
    const int wid = tid >> 6, lane = tid & 63;
    const int lm = lane & 15, lk = lane >> 4;
    const int rowbase = blockIdx.x * 64 + wid * 16;
    const int row = rowbase + lm;                 // this lane's batch row (col dim)

    // ---------- xB: B-fragments of GEMM1 (canonical slots) ----------
    // B[k][col=row]: k = 32*kt + 8*lk + jj, 8 contiguous floats per lane
    s16x8 xB[6];
    {
        const float* __restrict__ xr = x + (size_t)row * L;
        #pragma unroll
        for (int kt = 0; kt < 6; ++kt) {
            const int k0 = 32 * kt + 8 * lk;
            s16x8 v;
            if (k0 + 8 <= L) {
                float t[8];
                __builtin_memcpy(t, xr + k0, 32);
                #pragma unroll
                for (int jj = 0; jj < 8; ++jj) v[jj] = (short)f2bf(t[jj]);
            } else {
                #pragma unroll
                for (int jj = 0; jj < 8; ++jj) {
                    int k = k0 + jj;
                    v[jj] = (short)f2bf((k < L) ? xr[k] : 0.f);
                }
            }
            xB[kt] = v;
        }
    }

    // ---------- GEMM1 (flipped): Y^T[l][row], banded Toeplitz ----------
    f32x4 y[12];
    #pragma unroll
    for (int nt = 0; nt < 12; ++nt) y[nt] = (f32x4){0, 0, 0, 0};
    {
        constexpr int lo[12] = {0,0,0,0,1,1,2,2,3,3,4,4};
        constexpr int hi[12] = {1,1,2,2,3,3,4,4,5,5,5,5};
        #pragma unroll
        for (int nt = 0; nt < 12; ++nt) {
            #pragma unroll
            for (int kt = 0; kt < 6; ++kt) {
                if (kt >= lo[nt] && kt <= hi[nt]) {
                    s16x8 a = *(const s16x8*)(TtA + ((size_t)(nt * 6 + kt) * 64 + lane) * 8);
                    y[nt] = __builtin_amdgcn_mfma_f32_16x16x32_bf16(a, xB[kt], y[nt], 0, 0, 0);
                }
            }
        }
    }
    // lane holds Y for (l = 4*lk + j + 16*nt, row)

    // ---------- threshold -> spike count + spk B-fragments (permuted) ----------
    int scnt = 0;
    s16x8 spkB[6];
    #pragma unroll
    for (int kt = 0; kt < 6; ++kt) {
        union { unsigned w[4]; s16x8 v; } pk;
        #pragma unroll
        for (int w = 0; w < 4; ++w) {
            const int jj0 = 2 * w, jj1 = 2 * w + 1;
            const int nt0 = 2 * kt + (jj0 >> 2), j0 = jj0 & 3;
            const int nt1 = 2 * kt + (jj1 >> 2), j1 = jj1 & 3;
            bool s0 = y[nt0][j0] > YTH;
            bool s1 = y[nt1][j1] > YTH;
            scnt += (int)s0 + (int)s1;
            pk.w[w] = (s0 ? 0x3F80u : 0u) | (s1 ? 0x3F800000u : 0u);
        }
        spkB[kt] = pk.v;
    }
    #pragma unroll
    for (int off = 32; off; off >>= 1) scnt += __shfl_down(scnt, off);
    if (lane == 0) atomicAdd(cnt, (unsigned)scnt);

    // ---------- GEMM2 (flipped): cur1^T[h][row] ----------
    f32x4 cu[4];
    #pragma unroll
    for (int mt = 0; mt < 4; ++mt) cu[mt] = (f32x4){0, 0, 0, 0};
    #pragma unroll
    for (int mt = 0; mt < 4; ++mt)
        #pragma unroll
        for (int kt = 0; kt < 6; ++kt) {
            s16x8 a = *(const s16x8*)(W1A + ((size_t)(mt * 6 + kt) * 64 + lane) * 8);
            cu[mt] = __builtin_amdgcn_mfma_f32_16x16x32_bf16(a, spkB[kt], cu[mt], 0, 0, 0);
        }
    // lane holds cur1 for (h = 4*lk + j + 16*mt, row)

    // ---------- W2 A-fragments (8 uniform VGPRs) ----------
    s16x8 w2a[2];
    #pragma unroll
    for (int kt = 0; kt < 2; ++kt)
        w2a[kt] = *(const s16x8*)(W2A + ((size_t)kt * 64 + lane) * 8);

    // ---------- LIF: 25 steps, all in registers ----------
    f32x4 m1[4];
    #pragma unroll
    for (int mt = 0; mt < 4; ++mt) m1[mt] = (f32x4){0, 0, 0, 0};
    f32x4 m2 = (f32x4){0, 0, 0, 0};

    float* __restrict__ po = out + (size_t)row * 5;
    const size_t step = (size_t)B * 5;

    #pragma unroll 1
    for (int t = 0; t < NST; ++t) {
        // m1 update + spk1 pack into permuted B-fragments
        s16x8 s1b[2];
        #pragma unroll
        for (int kt = 0; kt < 2; ++kt) {
            union { unsigned w[4]; s16x8 v; } pk;
            #pragma unroll
            for (int w = 0; w < 4; ++w) {
                const int jj0 = 2 * w, jj1 = 2 * w + 1;
                const int mt0 = 2 * kt + (jj0 >> 2), j0 = jj0 & 3;
                const int mt1 = 2 * kt + (jj1 >> 2), j1 = jj1 & 3;
                float ma = fmaf(BETA, m1[mt0][j0], cu[mt0][j0]);
                float mb = fmaf(BETA, m1[mt1][j1], cu[mt1][j1]);
                bool sa = ma > 1.f, sb = mb > 1.f;
                m1[mt0][j0] = sa ? ma - 1.f : ma;
                m1[mt1][j1] = sb ? mb - 1.f : mb;
                pk.w[w] = (sa ? 0x3F80u : 0u) | (sb ? 0x3F800000u : 0u);
            }
            s1b[kt] = pk.v;
        }
        // cur2^T[c][row] via 2 MFMAs
        f32x4 c2 = (f32x4){0, 0, 0, 0};
        c2 = __builtin_amdgcn_mfma_f32_16x16x32_bf16(w2a[0], s1b[0], c2, 0, 0, 0);
        c2 = __builtin_amdgcn_mfma_f32_16x16x32_bf16(w2a[1], s1b[1], c2, 0, 0, 0);
        // m2 update (lane holds c = 4*lk + j for this row), store spikes
        f32x4 sv;
        #pragma unroll
        for (int j = 0; j < 4; ++j) {
            float m = fmaf(BETA, m2[j], c2[j]);
            bool s = m > 1.f;
            m2[j] = s ? m - 1.f : m;
            sv[j] = s ? 1.f : 0.f;
        }
        float* __restrict__ pt = po + (size_t)t * step;
        if (lk == 0) {
            __builtin_memcpy(pt, &sv, 16);        // c = 0..3
        } else if (lk == 1) {
            pt[4] = sv[0];                        // c = 4
        }
    }
}

__global__ void finalize_count(const unsigned int* __restrict__ cnt,
                               float* __restrict__ out, size_t off)
{
    if (threadIdx.x == 0 && blockIdx.x == 0)
        out[off] = (float)((double)(*cnt) * 25.0);
}

// ================= fallback (scalar), used only if ws too small ==============
__global__ void __launch_bounds__(256) snn_fallback(
    const float* __restrict__ x, const float* __restrict__ filt,
    const float* __restrict__ W1, const float* __restrict__ W2,
    float* __restrict__ out, unsigned int* __restrict__ cnt_ws, int B)
{
    const int row = blockIdx.x * 256 + threadIdx.x;
    const bool valid = row < B;
    const int rr = valid ? row : (B - 1);
    const float* __restrict__ xr = x + (size_t)rr * L;
    float w[64], cur1[H];
    #pragma unroll
    for (int h = 0; h < H; ++h) cur1[h] = 0.f;
    int cntv = 0;
    #pragma unroll
    for (int i = 0; i < 64; ++i) w[i] = (i >= 24) ? xr[i - 24] : 0.f;
    #pragma unroll 1
    for (int s = 0; s < 12; ++s) {
        const int l0 = s * 15;
        #pragma unroll
        for (int j = 0; j < 15; ++j) {
            const int l = l0 + j;
            float yv = 0.f;
            #pragma unroll
            for (int k = 0; k < 50; ++k) yv = fmaf(w[j + k], filt[k], yv);
            const bool sb = yv > YTH;
            cntv += sb;
            const float sp = sb ? 1.f : 0.f;
            #pragma unroll
            for (int h = 0; h < H; ++h) cur1[h] = fmaf(sp, W1[h * L + l], cur1[h]);
        }
        #pragma unroll
        for (int i = 0; i < 49; ++i) w[i] = w[i + 15];
        #pragma unroll
        for (int d = 0; d < 15; ++d) {
            const int g = l0 + 40 + d;
            w[49 + d] = (g < L) ? xr[g] : 0.f;
        }
    }
    #pragma unroll
    for (int j = 0; j < 7; ++j) {
        const int l = 180 + j;
        float yv = 0.f;
        #pragma unroll
        for (int k = 0; k < 50; ++k) yv = fmaf(w[j + k], filt[k], yv);
        const bool sb = yv > YTH;
        cntv += sb;
        const float sp = sb ? 1.f : 0.f;
        #pragma unroll
        for (int h = 0; h < H; ++h) cur1[h] = fmaf(sp, W1[h * L + l], cur1[h]);
    }
    int wc = valid ? cntv : 0;
    #pragma unroll
    for (int off = 32; off; off >>= 1) wc += __shfl_down(wc, off);
    if ((threadIdx.x & 63) == 0) atomicAdd(cnt_ws, (unsigned)wc);
    float m1[H], m2[5];
    #pragma unroll
    for (int h = 0; h < H; ++h) m1[h] = 0.f;
    #pragma unroll
    for (int c = 0; c < 5; ++c) m2[c] = 0.f;
    #pragma unroll 1
    for (int t = 0; t < NST; ++t) {
        float c2[5] = {0, 0, 0, 0, 0};
        #pragma unroll
        for (int h = 0; h < H; ++h) {
            float m = fmaf(BETA, m1[h], cur1[h]);
            const float sp = (m > 1.f) ? 1.f : 0.f;
            m1[h] = m - sp;
            #pragma unroll
            for (int c = 0; c < 5; ++c) c2[c] = fmaf(sp, W2[c * H + h], c2[c]);
        }
        float* __restrict__ ot = out + ((size_t)t * B + rr) * 5;
        #pragma unroll
        for (int c = 0; c < 5; ++c) {
            float m = fmaf(BETA, m2[c], c2[c]);
            const float s2 = (m > 1.f) ? 1.f : 0.f;
            m2[c] = m - s2;
            if (valid) ot[c] = s2;
        }
    }
}

extern "C" void kernel_launch(void* const* d_in, const int* in_sizes, int n_in,
                              void* d_out, int out_size, void* d_ws, size_t ws_size,
                              hipStream_t stream)
{
    const float* x    = (const float*)d_in[0];
    const float* filt = (const float*)d_in[1];
    const float* W1   = (const float*)d_in[2];
    const float* W2   = (const float*)d_in[3];
    float* out        = (float*)d_out;
    const int B       = in_sizes[0] / L;          // 131072

    unsigned int* cnt = (unsigned int*)d_ws;
    unsigned short* TtA = (unsigned short*)((char*)d_ws + 64);
    unsigned short* W1A = TtA + TTA_SH;
    unsigned short* W2A = W1A + W1A_SH;
    const size_t need = 64 + (size_t)(TTA_SH + W1A_SH + W2A_SH) * 2;

    hipMemsetAsync(cnt, 0, sizeof(unsigned int), stream);

    if (ws_size >= need && (B % 64) == 0) {
        const int total = TTA_SH + W1A_SH + W2A_SH;          // 50176
        prep_frags<<<(total + 255) / 256, 256, 0, stream>>>(filt, W1, W2, TtA, W1A, W2A);
        snn_main<<<B / 64, 256, 0, stream>>>(x, TtA, W1A, W2A, out, cnt, B);
    } else {
        snn_fallback<<<(B + 255) / 256, 256, 0, stream>>>(x, filt, W1, W2, out, cnt, B);
    }
    finalize_count<<<1, 1, 0, stream>>>(cnt, out, (size_t)NST * B * 5);
}